// Round 1
// baseline (2456.406 us; speedup 1.0000x reference)
//
#include <hip/hip_runtime.h>

#define DI __device__ __forceinline__

// Problem constants (B,C,T,F)=(2,256,1024,64), N=4, HID=64
static constexpr int B_ = 2;
static constexpr int C_ = 256;
static constexpr int T_ = 1024;
static constexpr int F_ = 64;
static constexpr int M_ = 8;      // N_*B_
static constexpr int E_ = 4096;   // HID*F = (C/N)*F
static constexpr float SCALE_ = 1.0f / 64.0f;   // 1/sqrt(4096)

DI unsigned short bf16_rne(float f) {
    unsigned int u = __float_as_uint(f);
    return (unsigned short)((u + 0x7FFFu + ((u >> 16) & 1u)) >> 16);
}
DI float bf2f(unsigned short h) { return __uint_as_float(((unsigned int)h) << 16); }
DI ushort4 pack4(float a, float b, float c, float d) {
    return make_ushort4(bf16_rne(a), bf16_rne(b), bf16_rne(c), bf16_rne(d));
}
DI float4 up4(ushort4 u) {
    return make_float4(bf2f(u.x), bf2f(u.y), bf2f(u.z), bf2f(u.w));
}

// ---------------------------------------------------------------------------
// K1: QKV projection.  Q/K/V[m=n*2+b][t][h*64+f] = sum_c x[b][c][t][f]*W[n][h][c] + bias
// block = (t, m), 128 threads, thread tile = 4h x 8f per projection.
// ---------------------------------------------------------------------------
__global__ __launch_bounds__(128) void qkv_kernel(
    const float* __restrict__ x,
    const float* __restrict__ Wq, const float* __restrict__ bq,
    const float* __restrict__ Wk, const float* __restrict__ bk,
    const float* __restrict__ Wv, const float* __restrict__ bv,
    unsigned short* __restrict__ Q, unsigned short* __restrict__ K,
    unsigned short* __restrict__ V)
{
    const int t = blockIdx.x;
    const int m = blockIdx.y;
    const int n = m >> 1, b = m & 1;
    const int tid = (int)threadIdx.x;
    const int hg = tid >> 3, fg = tid & 7;
    const int h0 = hg * 4, f0 = fg * 8;

    __shared__ float xs[32][64];   // [c-chunk][f]
    __shared__ float wqs[32][64];  // [c-chunk][h]
    __shared__ float wks[32][64];
    __shared__ float wvs[32][64];

    float aq[4][8], ak[4][8], av[4][8];
#pragma unroll
    for (int j = 0; j < 4; ++j)
#pragma unroll
        for (int i = 0; i < 8; ++i) { aq[j][i] = 0.f; ak[j][i] = 0.f; av[j][i] = 0.f; }

    const float* xb  = x  + (size_t)b * (C_ * T_ * F_) + (size_t)t * F_;
    const float* wqb = Wq + (size_t)n * (64 * 256);
    const float* wkb = Wk + (size_t)n * (64 * 256);
    const float* wvb = Wv + (size_t)n * (64 * 256);

    for (int ck = 0; ck < 8; ++ck) {
        const int cb = ck * 32;
#pragma unroll
        for (int it = 0; it < 4; ++it) {           // stage x slice (coalesced)
            int idx = it * 128 + tid;
            int cc = idx >> 4, f4 = (idx & 15) * 4;
            *(float4*)&xs[cc][f4] =
                *(const float4*)(xb + (size_t)(cb + cc) * (T_ * F_) + f4);
        }
#pragma unroll
        for (int it = 0; it < 4; ++it) {           // stage W chunks ([cc][h], L2-cached)
            int idx = it * 128 + tid;
            int h = idx & 63, cg = idx >> 6;
            int c = cb + cg * 4;
            float4 q4 = *(const float4*)(wqb + h * 256 + c);
            float4 k4 = *(const float4*)(wkb + h * 256 + c);
            float4 v4 = *(const float4*)(wvb + h * 256 + c);
            wqs[cg*4+0][h] = q4.x; wqs[cg*4+1][h] = q4.y; wqs[cg*4+2][h] = q4.z; wqs[cg*4+3][h] = q4.w;
            wks[cg*4+0][h] = k4.x; wks[cg*4+1][h] = k4.y; wks[cg*4+2][h] = k4.z; wks[cg*4+3][h] = k4.w;
            wvs[cg*4+0][h] = v4.x; wvs[cg*4+1][h] = v4.y; wvs[cg*4+2][h] = v4.z; wvs[cg*4+3][h] = v4.w;
        }
        __syncthreads();
        for (int cc = 0; cc < 32; ++cc) {
            float4 xa = *(float4*)&xs[cc][f0];
            float4 xc = *(float4*)&xs[cc][f0 + 4];
            float xv[8] = {xa.x, xa.y, xa.z, xa.w, xc.x, xc.y, xc.z, xc.w};
            float4 q4 = *(float4*)&wqs[cc][h0];
            float4 k4 = *(float4*)&wks[cc][h0];
            float4 v4 = *(float4*)&wvs[cc][h0];
            float qv[4] = {q4.x, q4.y, q4.z, q4.w};
            float kv[4] = {k4.x, k4.y, k4.z, k4.w};
            float vv[4] = {v4.x, v4.y, v4.z, v4.w};
#pragma unroll
            for (int j = 0; j < 4; ++j)
#pragma unroll
                for (int i = 0; i < 8; ++i) {
                    aq[j][i] = fmaf(qv[j], xv[i], aq[j][i]);
                    ak[j][i] = fmaf(kv[j], xv[i], ak[j][i]);
                    av[j][i] = fmaf(vv[j], xv[i], av[j][i]);
                }
        }
        __syncthreads();
    }

    unsigned short* qp = Q + ((size_t)m * T_ + t) * E_;
    unsigned short* kp = K + ((size_t)m * T_ + t) * E_;
    unsigned short* vp = V + ((size_t)m * T_ + t) * E_;
#pragma unroll
    for (int j = 0; j < 4; ++j) {
        int h = h0 + j;
        float bqv = bq[n * 64 + h], bkv = bk[n * 64 + h], bvv = bv[n * 64 + h];
        int e0 = h * 64 + f0;
        *(ushort4*)(qp + e0)     = pack4(aq[j][0]+bqv, aq[j][1]+bqv, aq[j][2]+bqv, aq[j][3]+bqv);
        *(ushort4*)(qp + e0 + 4) = pack4(aq[j][4]+bqv, aq[j][5]+bqv, aq[j][6]+bqv, aq[j][7]+bqv);
        *(ushort4*)(kp + e0)     = pack4(ak[j][0]+bkv, ak[j][1]+bkv, ak[j][2]+bkv, ak[j][3]+bkv);
        *(ushort4*)(kp + e0 + 4) = pack4(ak[j][4]+bkv, ak[j][5]+bkv, ak[j][6]+bkv, ak[j][7]+bkv);
        *(ushort4*)(vp + e0)     = pack4(av[j][0]+bvv, av[j][1]+bvv, av[j][2]+bvv, av[j][3]+bvv);
        *(ushort4*)(vp + e0 + 4) = pack4(av[j][4]+bvv, av[j][5]+bvv, av[j][6]+bvv, av[j][7]+bvv);
    }
}

// ---------------------------------------------------------------------------
// K2: S[m][t][s] = SCALE * sum_e Q[m][t][e]*K[m][s][e]   (NT GEMM, 128x128 tile)
// LDS tiles [row][32e] fp32 with XOR granule swizzle (granule p = g ^ ((row>>3)&7))
// to keep strided row reads 2-way (free) instead of 16-way conflicted.
// ---------------------------------------------------------------------------
__global__ __launch_bounds__(256) void scores_kernel(
    const unsigned short* __restrict__ Q, const unsigned short* __restrict__ K,
    unsigned short* __restrict__ S)
{
    const int m = blockIdx.z;
    const int tbase = blockIdx.y * 128;
    const int sbase = blockIdx.x * 128;
    const int tid = (int)threadIdx.x;
    const int tg = tid >> 4, sg = tid & 15;

    __shared__ float Qs[128 * 32];
    __shared__ float Ks[128 * 32];

    float acc[8][8];
#pragma unroll
    for (int i = 0; i < 8; ++i)
#pragma unroll
        for (int j = 0; j < 8; ++j) acc[i][j] = 0.f;

    const unsigned short* qrow = Q + ((size_t)m * T_ + tbase) * E_;
    const unsigned short* krow = K + ((size_t)m * T_ + sbase) * E_;

    for (int eb = 0; eb < E_; eb += 32) {
#pragma unroll
        for (int it = 0; it < 4; ++it) {
            int idx = it * 256 + tid;
            int row = idx >> 3, g = idx & 7;
            int p = g ^ ((row >> 3) & 7);
            *(float4*)&Qs[row * 32 + p * 4] = up4(*(const ushort4*)(qrow + (size_t)row * E_ + eb + g * 4));
            *(float4*)&Ks[row * 32 + p * 4] = up4(*(const ushort4*)(krow + (size_t)row * E_ + eb + g * 4));
        }
        __syncthreads();
        for (int g = 0; g < 8; ++g) {
            const int pk = (g ^ (sg & 7)) * 4;
            const int pq = (g ^ (tg & 7)) * 4;
            float4 kv[8];
#pragma unroll
            for (int j = 0; j < 8; ++j) kv[j] = *(float4*)&Ks[(sg * 8 + j) * 32 + pk];
#pragma unroll
            for (int i = 0; i < 8; ++i) {
                float4 qv = *(float4*)&Qs[(tg * 8 + i) * 32 + pq];
#pragma unroll
                for (int j = 0; j < 8; ++j) {
                    acc[i][j] = fmaf(qv.x, kv[j].x, acc[i][j]);
                    acc[i][j] = fmaf(qv.y, kv[j].y, acc[i][j]);
                    acc[i][j] = fmaf(qv.z, kv[j].z, acc[i][j]);
                    acc[i][j] = fmaf(qv.w, kv[j].w, acc[i][j]);
                }
            }
        }
        __syncthreads();
    }

#pragma unroll
    for (int i = 0; i < 8; ++i) {
        int trow = tbase + tg * 8 + i;
        unsigned short* sp = S + ((size_t)m * T_ + trow) * T_ + sbase + sg * 8;
        *(ushort4*)sp       = pack4(acc[i][0]*SCALE_, acc[i][1]*SCALE_, acc[i][2]*SCALE_, acc[i][3]*SCALE_);
        *(ushort4*)(sp + 4) = pack4(acc[i][4]*SCALE_, acc[i][5]*SCALE_, acc[i][6]*SCALE_, acc[i][7]*SCALE_);
    }
}

// ---------------------------------------------------------------------------
// K3: row softmax over s.  A[m][t][s] = softmax(S[m][t][:])[s]  (bf16 in/out)
// ---------------------------------------------------------------------------
__global__ __launch_bounds__(256) void softmax_kernel(
    const unsigned short* __restrict__ S, unsigned short* __restrict__ A)
{
    const size_t rowoff = ((size_t)blockIdx.y * T_ + blockIdx.x) * T_;
    const int tid = (int)threadIdx.x;
    const int wid = tid >> 6, lane = tid & 63;

    __shared__ float redmx[4];
    __shared__ float redsm[4];

    float4 v = up4(*(const ushort4*)(S + rowoff + tid * 4));
    float mx = fmaxf(fmaxf(v.x, v.y), fmaxf(v.z, v.w));
#pragma unroll
    for (int off = 32; off > 0; off >>= 1) mx = fmaxf(mx, __shfl_xor(mx, off));
    if (lane == 0) redmx[wid] = mx;
    __syncthreads();
    mx = fmaxf(fmaxf(redmx[0], redmx[1]), fmaxf(redmx[2], redmx[3]));

    float e0 = __expf(v.x - mx), e1 = __expf(v.y - mx);
    float e2 = __expf(v.z - mx), e3 = __expf(v.w - mx);
    float sm = (e0 + e1) + (e2 + e3);
#pragma unroll
    for (int off = 32; off > 0; off >>= 1) sm += __shfl_xor(sm, off);
    if (lane == 0) redsm[wid] = sm;
    __syncthreads();
    sm = (redsm[0] + redsm[1]) + (redsm[2] + redsm[3]);
    float inv = 1.0f / sm;
    *(ushort4*)(A + rowoff + tid * 4) = pack4(e0 * inv, e1 * inv, e2 * inv, e3 * inv);
}

// ---------------------------------------------------------------------------
// K4: Vo[m][t][d] = sum_s A[m][t][s]*V[m][s][d], written DIRECTLY in the
// torch-view-scrambled layout G[b][c][t2][f2]:
//   c = n*64 + (d>>6), t2 = (d&63)*16 + (t>>6), f2 = t&63   (m = n*2+b)
// 128t x 128d tile; thread tile 8t x (4+4)d.
// ---------------------------------------------------------------------------
__global__ __launch_bounds__(256) void pv_kernel(
    const unsigned short* __restrict__ A, const unsigned short* __restrict__ V,
    unsigned short* __restrict__ G)
{
    const int m = blockIdx.z;
    const int n = m >> 1, b = m & 1;
    const int tbase = blockIdx.y * 128;
    const int dbase = blockIdx.x * 128;
    const int tid = (int)threadIdx.x;
    const int tg = tid >> 4, dg = tid & 15;

    __shared__ float As[128 * 32];   // [t][s-chunk], swizzled
    __shared__ float Vs[32 * 128];   // [s-chunk][d]

    float acc[8][8];
#pragma unroll
    for (int i = 0; i < 8; ++i)
#pragma unroll
        for (int j = 0; j < 8; ++j) acc[i][j] = 0.f;

    const unsigned short* arow = A + ((size_t)m * T_ + tbase) * T_;
    const unsigned short* vrow = V + (size_t)m * T_ * E_ + dbase;

    for (int sb = 0; sb < T_; sb += 32) {
#pragma unroll
        for (int it = 0; it < 4; ++it) {
            int idx = it * 256 + tid;
            int row = idx >> 3, g = idx & 7;
            int p = g ^ ((row >> 3) & 7);
            *(float4*)&As[row * 32 + p * 4] = up4(*(const ushort4*)(arow + (size_t)row * T_ + sb + g * 4));
        }
#pragma unroll
        for (int it = 0; it < 4; ++it) {
            int idx = it * 256 + tid;
            int ss = idx >> 5, d4 = (idx & 31) * 4;
            *(float4*)&Vs[ss * 128 + d4] = up4(*(const ushort4*)(vrow + (size_t)(sb + ss) * E_ + d4));
        }
        __syncthreads();
        for (int ss = 0; ss < 32; ++ss) {
            float4 v0 = *(float4*)&Vs[ss * 128 + dg * 4];
            float4 v1 = *(float4*)&Vs[ss * 128 + dg * 4 + 64];
            float vv[8] = {v0.x, v0.y, v0.z, v0.w, v1.x, v1.y, v1.z, v1.w};
            const int pa = ((ss >> 2) ^ (tg & 7)) * 4 + (ss & 3);
#pragma unroll
            for (int i = 0; i < 8; ++i) {
                float a = As[(tg * 8 + i) * 32 + pa];
#pragma unroll
                for (int jj = 0; jj < 8; ++jj)
                    acc[i][jj] = fmaf(a, vv[jj], acc[i][jj]);
            }
        }
        __syncthreads();
    }

    const int trow_hi = (tbase + tg * 8) >> 6;   // t>>6, constant per thread
    const int f2b = (tg & 7) * 8;                // t&63 base, 8-aligned run over i
#pragma unroll
    for (int jj = 0; jj < 8; ++jj) {
        int d = dbase + ((jj >> 2) << 6) + dg * 4 + (jj & 3);
        int c = n * 64 + (d >> 6);
        int t2 = (d & 63) * 16 + trow_hi;
        unsigned short* gp = G + (((size_t)(b * 256 + c)) * 1024 + t2) * 64 + f2b;
        *(ushort4*)gp       = pack4(acc[0][jj], acc[1][jj], acc[2][jj], acc[3][jj]);
        *(ushort4*)(gp + 4) = pack4(acc[4][jj], acc[5][jj], acc[6][jj], acc[7][jj]);
    }
}

// ---------------------------------------------------------------------------
// K5: out[b][o][t][f] = sum_c Wp[o][c]*G[b][c][t][f] + bp[o] + x[b][o][t][f]
// block = (t, b), 256 threads, thread tile 8o x 8f.
// ---------------------------------------------------------------------------
__global__ __launch_bounds__(256) void outproj_kernel(
    const unsigned short* __restrict__ G, const float* __restrict__ Wp,
    const float* __restrict__ bp, const float* __restrict__ x,
    float* __restrict__ out)
{
    const int t = blockIdx.x;
    const int b = blockIdx.y;
    const int tid = (int)threadIdx.x;
    const int og = tid >> 3, fg = tid & 7;
    const int o0 = og * 8, f0 = fg * 8;

    __shared__ float gs[32][64];     // [c-chunk][f]
    __shared__ float wps[32][256];   // [c-chunk][o]

    float acc[8][8];
#pragma unroll
    for (int j = 0; j < 8; ++j)
#pragma unroll
        for (int i = 0; i < 8; ++i) acc[j][i] = 0.f;

    const unsigned short* gb = G + (size_t)b * (C_ * T_ * F_) + (size_t)t * F_;

    for (int ck = 0; ck < 8; ++ck) {
        const int cb = ck * 32;
#pragma unroll
        for (int it = 0; it < 2; ++it) {
            int idx = it * 256 + tid;
            int cc = idx >> 4, f4 = (idx & 15) * 4;
            *(float4*)&gs[cc][f4] = up4(*(const ushort4*)(gb + (size_t)(cb + cc) * (T_ * F_) + f4));
        }
#pragma unroll
        for (int cg = 0; cg < 8; ++cg) {          // thread tid owns column o=tid
            float4 w4 = *(const float4*)(Wp + (size_t)tid * 256 + cb + cg * 4);
            wps[cg*4+0][tid] = w4.x; wps[cg*4+1][tid] = w4.y;
            wps[cg*4+2][tid] = w4.z; wps[cg*4+3][tid] = w4.w;
        }
        __syncthreads();
        for (int cc = 0; cc < 32; ++cc) {
            float4 g0 = *(float4*)&gs[cc][f0];
            float4 g1 = *(float4*)&gs[cc][f0 + 4];
            float gv[8] = {g0.x, g0.y, g0.z, g0.w, g1.x, g1.y, g1.z, g1.w};
            float4 w0 = *(float4*)&wps[cc][o0];
            float4 w1 = *(float4*)&wps[cc][o0 + 4];
            float wv[8] = {w0.x, w0.y, w0.z, w0.w, w1.x, w1.y, w1.z, w1.w};
#pragma unroll
            for (int j = 0; j < 8; ++j)
#pragma unroll
                for (int i = 0; i < 8; ++i)
                    acc[j][i] = fmaf(wv[j], gv[i], acc[j][i]);
        }
        __syncthreads();
    }

    const float* xrow = x   + (size_t)b * (C_ * T_ * F_) + (size_t)t * F_;
    float* orow       = out + (size_t)b * (C_ * T_ * F_) + (size_t)t * F_;
#pragma unroll
    for (int j = 0; j < 8; ++j) {
        int o = o0 + j;
        float bias = bp[o];
        const float* xp = xrow + (size_t)o * (T_ * F_) + f0;
        float* op       = orow + (size_t)o * (T_ * F_) + f0;
        float4 xv0 = *(const float4*)xp;
        float4 xv1 = *(const float4*)(xp + 4);
        float4 r0 = make_float4(acc[j][0]+bias+xv0.x, acc[j][1]+bias+xv0.y,
                                acc[j][2]+bias+xv0.z, acc[j][3]+bias+xv0.w);
        float4 r1 = make_float4(acc[j][4]+bias+xv1.x, acc[j][5]+bias+xv1.y,
                                acc[j][6]+bias+xv1.z, acc[j][7]+bias+xv1.w);
        *(float4*)op       = r0;
        *(float4*)(op + 4) = r1;
    }
}

// ---------------------------------------------------------------------------
extern "C" void kernel_launch(void* const* d_in, const int* in_sizes, int n_in,
                              void* d_out, int out_size, void* d_ws, size_t ws_size,
                              hipStream_t stream) {
    const float* x  = (const float*)d_in[0];
    const float* Wq = (const float*)d_in[1];
    const float* bq = (const float*)d_in[2];
    const float* Wk = (const float*)d_in[3];
    const float* bk = (const float*)d_in[4];
    const float* Wv = (const float*)d_in[5];
    const float* bv = (const float*)d_in[6];
    const float* Wp = (const float*)d_in[7];
    const float* bp = (const float*)d_in[8];
    float* out = (float*)d_out;

    // workspace layout (235 MB total)
    char* ws = (char*)d_ws;
    unsigned short* Q = (unsigned short*)(ws);                    // 67,108,864 B
    unsigned short* K = (unsigned short*)(ws + 67108864);         // 67,108,864 B
    unsigned short* V = (unsigned short*)(ws + 134217728);        // 67,108,864 B
    unsigned short* S = (unsigned short*)(ws + 201326592);        // 16,777,216 B
    unsigned short* A = (unsigned short*)(ws + 218103808);        // 16,777,216 B
    unsigned short* G = Q;  // PV output reuses Q's region (Q is dead by then)

    qkv_kernel<<<dim3(T_, M_), 128, 0, stream>>>(x, Wq, bq, Wk, bk, Wv, bv, Q, K, V);
    scores_kernel<<<dim3(8, 8, M_), 256, 0, stream>>>(Q, K, S);
    softmax_kernel<<<dim3(T_, M_), 256, 0, stream>>>(S, A);
    pv_kernel<<<dim3(32, 8, M_), 256, 0, stream>>>(A, V, G);
    outproj_kernel<<<dim3(T_, B_), 256, 0, stream>>>(G, Wp, bp, x, out);
}

// Round 2
// 1084.132 us; speedup vs baseline: 2.2658x; 2.2658x over previous
//
#include <hip/hip_runtime.h>

#define DI __device__ __forceinline__

// Problem constants (B,C,T,F)=(2,256,1024,64), N=4, HID=64
static constexpr int B_ = 2;
static constexpr int C_ = 256;
static constexpr int T_ = 1024;
static constexpr int F_ = 64;
static constexpr int M_ = 8;      // N_*B_
static constexpr int E_ = 4096;   // HID*F = (C/N)*F
static constexpr float SCALE_ = 1.0f / 64.0f;   // 1/sqrt(4096)

typedef __attribute__((ext_vector_type(8))) short bf16x8;
typedef __attribute__((ext_vector_type(4))) float f32x4;

DI unsigned short bf16_rne(float f) {
    unsigned int u = __float_as_uint(f);
    return (unsigned short)((u + 0x7FFFu + ((u >> 16) & 1u)) >> 16);
}
DI float bf2f(unsigned short h) { return __uint_as_float(((unsigned int)h) << 16); }
DI ushort4 pack4(float a, float b, float c, float d) {
    return make_ushort4(bf16_rne(a), bf16_rne(b), bf16_rne(c), bf16_rne(d));
}
DI float4 up4(ushort4 u) {
    return make_float4(bf2f(u.x), bf2f(u.y), bf2f(u.z), bf2f(u.w));
}

// async global->LDS, 16B per lane; LDS dest = wave-uniform base + lane*16
DI void gload_lds16(const unsigned short* g, unsigned short* l) {
    __builtin_amdgcn_global_load_lds(
        (const __attribute__((address_space(1))) unsigned int*)g,
        (__attribute__((address_space(3))) unsigned int*)l, 16, 0, 0);
}

// MFMA via inline asm (shape per cdna4_isa §10: A=4 VGPR, B=4 VGPR, C/D=4)
DI void mfma16(f32x4& acc, bf16x8 a, bf16x8 b) {
    asm("v_mfma_f32_16x16x32_bf16 %0, %1, %2, %0" : "+v"(acc) : "v"(a), "v"(b));
}

// ---------------------------------------------------------------------------
// K1: QKV projection (unchanged, VALU).  Q/K/V[m][t][h*64+f] = sum_c x*W + b
// ---------------------------------------------------------------------------
__global__ __launch_bounds__(128) void qkv_kernel(
    const float* __restrict__ x,
    const float* __restrict__ Wq, const float* __restrict__ bq,
    const float* __restrict__ Wk, const float* __restrict__ bk,
    const float* __restrict__ Wv, const float* __restrict__ bv,
    unsigned short* __restrict__ Q, unsigned short* __restrict__ K,
    unsigned short* __restrict__ V)
{
    const int t = blockIdx.x;
    const int m = blockIdx.y;
    const int n = m >> 1, b = m & 1;
    const int tid = (int)threadIdx.x;
    const int hg = tid >> 3, fg = tid & 7;
    const int h0 = hg * 4, f0 = fg * 8;

    __shared__ float xs[32][64];
    __shared__ float wqs[32][64];
    __shared__ float wks[32][64];
    __shared__ float wvs[32][64];

    float aq[4][8], ak[4][8], av[4][8];
#pragma unroll
    for (int j = 0; j < 4; ++j)
#pragma unroll
        for (int i = 0; i < 8; ++i) { aq[j][i] = 0.f; ak[j][i] = 0.f; av[j][i] = 0.f; }

    const float* xb  = x  + (size_t)b * (C_ * T_ * F_) + (size_t)t * F_;
    const float* wqb = Wq + (size_t)n * (64 * 256);
    const float* wkb = Wk + (size_t)n * (64 * 256);
    const float* wvb = Wv + (size_t)n * (64 * 256);

    for (int ck = 0; ck < 8; ++ck) {
        const int cb = ck * 32;
#pragma unroll
        for (int it = 0; it < 4; ++it) {
            int idx = it * 128 + tid;
            int cc = idx >> 4, f4 = (idx & 15) * 4;
            *(float4*)&xs[cc][f4] =
                *(const float4*)(xb + (size_t)(cb + cc) * (T_ * F_) + f4);
        }
#pragma unroll
        for (int it = 0; it < 4; ++it) {
            int idx = it * 128 + tid;
            int h = idx & 63, cg = idx >> 6;
            int c = cb + cg * 4;
            float4 q4 = *(const float4*)(wqb + h * 256 + c);
            float4 k4 = *(const float4*)(wkb + h * 256 + c);
            float4 v4 = *(const float4*)(wvb + h * 256 + c);
            wqs[cg*4+0][h] = q4.x; wqs[cg*4+1][h] = q4.y; wqs[cg*4+2][h] = q4.z; wqs[cg*4+3][h] = q4.w;
            wks[cg*4+0][h] = k4.x; wks[cg*4+1][h] = k4.y; wks[cg*4+2][h] = k4.z; wks[cg*4+3][h] = k4.w;
            wvs[cg*4+0][h] = v4.x; wvs[cg*4+1][h] = v4.y; wvs[cg*4+2][h] = v4.z; wvs[cg*4+3][h] = v4.w;
        }
        __syncthreads();
        for (int cc = 0; cc < 32; ++cc) {
            float4 xa = *(float4*)&xs[cc][f0];
            float4 xc = *(float4*)&xs[cc][f0 + 4];
            float xv[8] = {xa.x, xa.y, xa.z, xa.w, xc.x, xc.y, xc.z, xc.w};
            float4 q4 = *(float4*)&wqs[cc][h0];
            float4 k4 = *(float4*)&wks[cc][h0];
            float4 v4 = *(float4*)&wvs[cc][h0];
            float qv[4] = {q4.x, q4.y, q4.z, q4.w};
            float kv[4] = {k4.x, k4.y, k4.z, k4.w};
            float vv[4] = {v4.x, v4.y, v4.z, v4.w};
#pragma unroll
            for (int j = 0; j < 4; ++j)
#pragma unroll
                for (int i = 0; i < 8; ++i) {
                    aq[j][i] = fmaf(qv[j], xv[i], aq[j][i]);
                    ak[j][i] = fmaf(kv[j], xv[i], ak[j][i]);
                    av[j][i] = fmaf(vv[j], xv[i], av[j][i]);
                }
        }
        __syncthreads();
    }

    unsigned short* qp = Q + ((size_t)m * T_ + t) * E_;
    unsigned short* kp = K + ((size_t)m * T_ + t) * E_;
    unsigned short* vp = V + ((size_t)m * T_ + t) * E_;
#pragma unroll
    for (int j = 0; j < 4; ++j) {
        int h = h0 + j;
        float bqv = bq[n * 64 + h], bkv = bk[n * 64 + h], bvv = bv[n * 64 + h];
        int e0 = h * 64 + f0;
        *(ushort4*)(qp + e0)     = pack4(aq[j][0]+bqv, aq[j][1]+bqv, aq[j][2]+bqv, aq[j][3]+bqv);
        *(ushort4*)(qp + e0 + 4) = pack4(aq[j][4]+bqv, aq[j][5]+bqv, aq[j][6]+bqv, aq[j][7]+bqv);
        *(ushort4*)(kp + e0)     = pack4(ak[j][0]+bkv, ak[j][1]+bkv, ak[j][2]+bkv, ak[j][3]+bkv);
        *(ushort4*)(kp + e0 + 4) = pack4(ak[j][4]+bkv, ak[j][5]+bkv, ak[j][6]+bkv, ak[j][7]+bkv);
        *(ushort4*)(vp + e0)     = pack4(av[j][0]+bvv, av[j][1]+bvv, av[j][2]+bvv, av[j][3]+bvv);
        *(ushort4*)(vp + e0 + 4) = pack4(av[j][4]+bvv, av[j][5]+bvv, av[j][6]+bvv, av[j][7]+bvv);
    }
}

// ---------------------------------------------------------------------------
// K2: scores, MFMA NT GEMM. S[m][t][s] = SCALE * sum_e Q[t][e] K[s][e]
// 128x128 tile, BK=64, 4 waves (2x2), 4x4 16x16 fragments per wave.
// LDS tile [128 rows][64 bf16], phys_byte = row*128 + (bytecol ^ ((row&7)<<4)).
// Staged via global_load_lds (linear dest) with inverse-swizzled global source.
// ---------------------------------------------------------------------------
__global__ __launch_bounds__(256) void scores_mfma(
    const unsigned short* __restrict__ Q, const unsigned short* __restrict__ K,
    unsigned short* __restrict__ S)
{
    const int m = blockIdx.z;
    const int tbase = blockIdx.y * 128;
    const int sbase = blockIdx.x * 128;
    const int tid = (int)threadIdx.x;
    const int wid = tid >> 6, lane = tid & 63;
    const int wr = wid >> 1, wc = wid & 1;
    const int lo16 = lane & 15, hi4 = lane >> 4;

    __shared__ unsigned short As[128 * 64];
    __shared__ unsigned short Bs[128 * 64];

    f32x4 acc[4][4] = {};

    const unsigned short* qrow = Q + ((size_t)m * T_ + tbase) * E_;
    const unsigned short* krow = K + ((size_t)m * T_ + sbase) * E_;

    const int srow = lane >> 3;                        // 0..7 (row within 8-row chunk)
    const int scol = ((lane & 7) ^ srow) * 8;          // inverse-swizzled source col (elems)

    for (int eb = 0; eb < E_; eb += 64) {
#pragma unroll
        for (int i = 0; i < 4; ++i) {
            const int rb = wid * 32 + i * 8;           // wave-uniform row base
            gload_lds16(qrow + (size_t)(rb + srow) * E_ + eb + scol, &As[rb * 64]);
            gload_lds16(krow + (size_t)(rb + srow) * E_ + eb + scol, &Bs[rb * 64]);
        }
        __syncthreads();
#pragma unroll
        for (int kk = 0; kk < 2; ++kk) {
            const int hc = (kk * 32 + hi4 * 8) ^ ((lane & 7) << 3);   // swizzled read (halves)
            bf16x8 a[4], bb[4];
#pragma unroll
            for (int mi = 0; mi < 4; ++mi)
                a[mi] = *(const bf16x8*)&As[(wr * 64 + mi * 16 + lo16) * 64 + hc];
#pragma unroll
            for (int nj = 0; nj < 4; ++nj)
                bb[nj] = *(const bf16x8*)&Bs[(wc * 64 + nj * 16 + lo16) * 64 + hc];
#pragma unroll
            for (int mi = 0; mi < 4; ++mi)
#pragma unroll
                for (int nj = 0; nj < 4; ++nj)
                    mfma16(acc[mi][nj], a[mi], bb[nj]);
        }
        __syncthreads();
    }

    asm volatile("s_nop 7\n\ts_nop 7" ::: "memory");   // MFMA->VALU hazard guard
    // C/D layout: col = lane&15, row = (lane>>4)*4 + reg
#pragma unroll
    for (int mi = 0; mi < 4; ++mi)
#pragma unroll
        for (int r = 0; r < 4; ++r) {
            int trow = tbase + wr * 64 + mi * 16 + hi4 * 4 + r;
            unsigned short* sp = S + ((size_t)m * T_ + trow) * T_ + sbase + wc * 64 + lo16;
#pragma unroll
            for (int nj = 0; nj < 4; ++nj)
                sp[nj * 16] = bf16_rne(acc[mi][nj][r] * SCALE_);
        }
}

// ---------------------------------------------------------------------------
// K3: row softmax (unchanged)
// ---------------------------------------------------------------------------
__global__ __launch_bounds__(256) void softmax_kernel(
    const unsigned short* __restrict__ S, unsigned short* __restrict__ A)
{
    const size_t rowoff = ((size_t)blockIdx.y * T_ + blockIdx.x) * T_;
    const int tid = (int)threadIdx.x;
    const int wid = tid >> 6, lane = tid & 63;

    __shared__ float redmx[4];
    __shared__ float redsm[4];

    float4 v = up4(*(const ushort4*)(S + rowoff + tid * 4));
    float mx = fmaxf(fmaxf(v.x, v.y), fmaxf(v.z, v.w));
#pragma unroll
    for (int off = 32; off > 0; off >>= 1) mx = fmaxf(mx, __shfl_xor(mx, off));
    if (lane == 0) redmx[wid] = mx;
    __syncthreads();
    mx = fmaxf(fmaxf(redmx[0], redmx[1]), fmaxf(redmx[2], redmx[3]));

    float e0 = __expf(v.x - mx), e1 = __expf(v.y - mx);
    float e2 = __expf(v.z - mx), e3 = __expf(v.w - mx);
    float sm = (e0 + e1) + (e2 + e3);
#pragma unroll
    for (int off = 32; off > 0; off >>= 1) sm += __shfl_xor(sm, off);
    if (lane == 0) redsm[wid] = sm;
    __syncthreads();
    sm = (redsm[0] + redsm[1]) + (redsm[2] + redsm[3]);
    float inv = 1.0f / sm;
    *(ushort4*)(A + rowoff + tid * 4) = pack4(e0 * inv, e1 * inv, e2 * inv, e3 * inv);
}

// ---------------------------------------------------------------------------
// K3b: V transpose.  Vt[m][d][s] = V[m][s][d]   (64x64 tiles)
// ---------------------------------------------------------------------------
__global__ __launch_bounds__(256) void vt_kernel(
    const unsigned short* __restrict__ V, unsigned short* __restrict__ Vt)
{
    const int m = blockIdx.z;
    const int d0 = blockIdx.x * 64;
    const int s0 = blockIdx.y * 64;
    const int tid = (int)threadIdx.x;
    __shared__ unsigned short ts[64][68];   // pad 68: 8B-aligned rows, spread banks

    const unsigned short* vp = V + (size_t)m * T_ * E_;
#pragma unroll
    for (int it = 0; it < 4; ++it) {
        int idx = it * 256 + tid;
        int sl = idx >> 4, d4 = (idx & 15) * 4;
        *(ushort4*)&ts[sl][d4] = *(const ushort4*)&vp[(size_t)(s0 + sl) * E_ + d0 + d4];
    }
    __syncthreads();
    unsigned short* op = Vt + (size_t)m * E_ * T_;
    const int dl = tid >> 2, s16 = (tid & 3) * 16;
#pragma unroll
    for (int q = 0; q < 4; ++q) {
        int s4 = s16 + q * 4;
        ushort4 v = make_ushort4(ts[s4][dl], ts[s4+1][dl], ts[s4+2][dl], ts[s4+3][dl]);
        *(ushort4*)&op[(size_t)(d0 + dl) * T_ + s0 + s4] = v;
    }
}

// ---------------------------------------------------------------------------
// K4: PV, MFMA NT GEMM vs Vt.  Vo[m][t][d] = sum_s A[t][s] Vt[d][s], written
// directly in scrambled layout G[b][c][t2][f2] (verified in round 0):
//   c = n*64 + (d>>6), t2 = (d&63)*16 + (t>>6), f2 = t&63
// ---------------------------------------------------------------------------
__global__ __launch_bounds__(256) void pv_mfma(
    const unsigned short* __restrict__ A, const unsigned short* __restrict__ Vt,
    unsigned short* __restrict__ G)
{
    const int m = blockIdx.z;
    const int nh = m >> 1, b = m & 1;
    const int tbase = blockIdx.y * 128;
    const int dbase = blockIdx.x * 128;
    const int tid = (int)threadIdx.x;
    const int wid = tid >> 6, lane = tid & 63;
    const int wr = wid >> 1, wc = wid & 1;
    const int lo16 = lane & 15, hi4 = lane >> 4;

    __shared__ unsigned short As[128 * 64];
    __shared__ unsigned short Bs[128 * 64];

    f32x4 acc[4][4] = {};

    const unsigned short* arow = A  + ((size_t)m * T_ + tbase) * T_;
    const unsigned short* vrow = Vt + (size_t)m * E_ * T_ + (size_t)dbase * T_;

    const int srow = lane >> 3;
    const int scol = ((lane & 7) ^ srow) * 8;

    for (int sb = 0; sb < T_; sb += 64) {
#pragma unroll
        for (int i = 0; i < 4; ++i) {
            const int rb = wid * 32 + i * 8;
            gload_lds16(arow + (size_t)(rb + srow) * T_ + sb + scol, &As[rb * 64]);
            gload_lds16(vrow + (size_t)(rb + srow) * T_ + sb + scol, &Bs[rb * 64]);
        }
        __syncthreads();
#pragma unroll
        for (int kk = 0; kk < 2; ++kk) {
            const int hc = (kk * 32 + hi4 * 8) ^ ((lane & 7) << 3);
            bf16x8 a[4], bb[4];
#pragma unroll
            for (int mi = 0; mi < 4; ++mi)
                a[mi] = *(const bf16x8*)&As[(wr * 64 + mi * 16 + lo16) * 64 + hc];
#pragma unroll
            for (int nj = 0; nj < 4; ++nj)
                bb[nj] = *(const bf16x8*)&Bs[(wc * 64 + nj * 16 + lo16) * 64 + hc];
#pragma unroll
            for (int mi = 0; mi < 4; ++mi)
#pragma unroll
                for (int nj = 0; nj < 4; ++nj)
                    mfma16(acc[mi][nj], a[mi], bb[nj]);
        }
        __syncthreads();
    }

    asm volatile("s_nop 7\n\ts_nop 7" ::: "memory");
    const int cb   = nh * 64 + (dbase >> 6) + wc;     // c channel (const per wave col)
    const int t2lo = (tbase >> 6) + wr;               // t>>6 (const per wave row)
#pragma unroll
    for (int mi = 0; mi < 4; ++mi) {
        const int tl = mi * 16 + hi4 * 4;             // f2 base (t&63), 4-aligned
#pragma unroll
        for (int nj = 0; nj < 4; ++nj) {
            const int d63 = nj * 16 + lo16;           // d&63
            size_t addr = (((size_t)(b * 256 + cb)) * 1024 + d63 * 16 + t2lo) * 64 + tl;
            *(ushort4*)&G[addr] = pack4(acc[mi][nj][0], acc[mi][nj][1],
                                        acc[mi][nj][2], acc[mi][nj][3]);
        }
    }
}

// ---------------------------------------------------------------------------
// K5: out projection + bias + residual (unchanged)
// ---------------------------------------------------------------------------
__global__ __launch_bounds__(256) void outproj_kernel(
    const unsigned short* __restrict__ G, const float* __restrict__ Wp,
    const float* __restrict__ bp, const float* __restrict__ x,
    float* __restrict__ out)
{
    const int t = blockIdx.x;
    const int b = blockIdx.y;
    const int tid = (int)threadIdx.x;
    const int og = tid >> 3, fg = tid & 7;
    const int o0 = og * 8, f0 = fg * 8;

    __shared__ float gs[32][64];
    __shared__ float wps[32][256];

    float acc[8][8];
#pragma unroll
    for (int j = 0; j < 8; ++j)
#pragma unroll
        for (int i = 0; i < 8; ++i) acc[j][i] = 0.f;

    const unsigned short* gb = G + (size_t)b * (C_ * T_ * F_) + (size_t)t * F_;

    for (int ck = 0; ck < 8; ++ck) {
        const int cb = ck * 32;
#pragma unroll
        for (int it = 0; it < 2; ++it) {
            int idx = it * 256 + tid;
            int cc = idx >> 4, f4 = (idx & 15) * 4;
            *(float4*)&gs[cc][f4] = up4(*(const ushort4*)(gb + (size_t)(cb + cc) * (T_ * F_) + f4));
        }
#pragma unroll
        for (int cg = 0; cg < 8; ++cg) {
            float4 w4 = *(const float4*)(Wp + (size_t)tid * 256 + cb + cg * 4);
            wps[cg*4+0][tid] = w4.x; wps[cg*4+1][tid] = w4.y;
            wps[cg*4+2][tid] = w4.z; wps[cg*4+3][tid] = w4.w;
        }
        __syncthreads();
        for (int cc = 0; cc < 32; ++cc) {
            float4 g0 = *(float4*)&gs[cc][f0];
            float4 g1 = *(float4*)&gs[cc][f0 + 4];
            float gv[8] = {g0.x, g0.y, g0.z, g0.w, g1.x, g1.y, g1.z, g1.w};
            float4 w0 = *(float4*)&wps[cc][o0];
            float4 w1 = *(float4*)&wps[cc][o0 + 4];
            float wv[8] = {w0.x, w0.y, w0.z, w0.w, w1.x, w1.y, w1.z, w1.w};
#pragma unroll
            for (int j = 0; j < 8; ++j)
#pragma unroll
                for (int i = 0; i < 8; ++i)
                    acc[j][i] = fmaf(wv[j], gv[i], acc[j][i]);
        }
        __syncthreads();
    }

    const float* xrow = x   + (size_t)b * (C_ * T_ * F_) + (size_t)t * F_;
    float* orow       = out + (size_t)b * (C_ * T_ * F_) + (size_t)t * F_;
#pragma unroll
    for (int j = 0; j < 8; ++j) {
        int o = o0 + j;
        float bias = bp[o];
        const float* xp = xrow + (size_t)o * (T_ * F_) + f0;
        float* op       = orow + (size_t)o * (T_ * F_) + f0;
        float4 xv0 = *(const float4*)xp;
        float4 xv1 = *(const float4*)(xp + 4);
        float4 r0 = make_float4(acc[j][0]+bias+xv0.x, acc[j][1]+bias+xv0.y,
                                acc[j][2]+bias+xv0.z, acc[j][3]+bias+xv0.w);
        float4 r1 = make_float4(acc[j][4]+bias+xv1.x, acc[j][5]+bias+xv1.y,
                                acc[j][6]+bias+xv1.z, acc[j][7]+bias+xv1.w);
        *(float4*)op       = r0;
        *(float4*)(op + 4) = r1;
    }
}

// ---------------------------------------------------------------------------
extern "C" void kernel_launch(void* const* d_in, const int* in_sizes, int n_in,
                              void* d_out, int out_size, void* d_ws, size_t ws_size,
                              hipStream_t stream) {
    const float* x  = (const float*)d_in[0];
    const float* Wq = (const float*)d_in[1];
    const float* bq = (const float*)d_in[2];
    const float* Wk = (const float*)d_in[3];
    const float* bk = (const float*)d_in[4];
    const float* Wv = (const float*)d_in[5];
    const float* bv = (const float*)d_in[6];
    const float* Wp = (const float*)d_in[7];
    const float* bp = (const float*)d_in[8];
    float* out = (float*)d_out;

    // workspace layout (224 MB total)
    char* ws = (char*)d_ws;
    unsigned short* Q  = (unsigned short*)(ws);                    // 64 MB
    unsigned short* K  = (unsigned short*)(ws + 67108864);         // 64 MB
    unsigned short* V  = (unsigned short*)(ws + 134217728);        // 64 MB
    unsigned short* S  = (unsigned short*)(ws + 201326592);        // 16 MB
    unsigned short* A  = (unsigned short*)(ws + 218103808);        // 16 MB
    unsigned short* Vt = K;  // K dead after scores
    unsigned short* G  = Q;  // Q dead after scores

    qkv_kernel<<<dim3(T_, M_), 128, 0, stream>>>(x, Wq, bq, Wk, bk, Wv, bv, Q, K, V);
    scores_mfma<<<dim3(8, 8, M_), 256, 0, stream>>>(Q, K, S);
    softmax_kernel<<<dim3(T_, M_), 256, 0, stream>>>(S, A);
    vt_kernel<<<dim3(64, 16, M_), 256, 0, stream>>>(V, Vt);
    pv_mfma<<<dim3(32, 8, M_), 256, 0, stream>>>(A, Vt, G);
    outproj_kernel<<<dim3(T_, B_), 256, 0, stream>>>(G, Wp, bp, x, out);
}

// Round 3
// 533.849 us; speedup vs baseline: 4.6013x; 2.0308x over previous
//
#include <hip/hip_runtime.h>

#define DI __device__ __forceinline__

// Problem constants (B,C,T,F)=(2,256,1024,64), N=4, HID=64
static constexpr int B_ = 2;
static constexpr int C_ = 256;
static constexpr int T_ = 1024;
static constexpr int F_ = 64;
static constexpr int M_ = 8;      // N_*B_
static constexpr int E_ = 4096;   // HID*F = (C/N)*F
static constexpr float SCALE_ = 1.0f / 64.0f;   // 1/sqrt(4096)

typedef __attribute__((ext_vector_type(8))) short bf16x8;
typedef __attribute__((ext_vector_type(4))) float f32x4;

DI unsigned short bf16_rne(float f) {
    unsigned int u = __float_as_uint(f);
    return (unsigned short)((u + 0x7FFFu + ((u >> 16) & 1u)) >> 16);
}
DI float bf2f(unsigned short h) { return __uint_as_float(((unsigned int)h) << 16); }
DI ushort4 pack4(float a, float b, float c, float d) {
    return make_ushort4(bf16_rne(a), bf16_rne(b), bf16_rne(c), bf16_rne(d));
}
DI float4 up4(ushort4 u) {
    return make_float4(bf2f(u.x), bf2f(u.y), bf2f(u.z), bf2f(u.w));
}

// async global->LDS, 16B per lane; LDS dest = wave-uniform base + lane*16
DI void gload_lds16(const unsigned short* g, unsigned short* l) {
    __builtin_amdgcn_global_load_lds(
        (const __attribute__((address_space(1))) unsigned int*)g,
        (__attribute__((address_space(3))) unsigned int*)l, 16, 0, 0);
}

DI void mfma16(f32x4& acc, bf16x8 a, bf16x8 b) {
    asm("v_mfma_f32_16x16x32_bf16 %0, %1, %2, %0" : "+v"(acc) : "v"(a), "v"(b));
}

// ---------------------------------------------------------------------------
// K0: convert Wq|Wk|Wv (fp32 [4][64][256] each) -> Wall bf16 [768][256],
//     and bias_all[768] = bq|bk|bv.
// ---------------------------------------------------------------------------
__global__ __launch_bounds__(256) void wconv_kernel(
    const float* __restrict__ Wq, const float* __restrict__ Wk,
    const float* __restrict__ Wv, const float* __restrict__ bq,
    const float* __restrict__ bk, const float* __restrict__ bv,
    unsigned short* __restrict__ Wall, float* __restrict__ bias_all)
{
    const int tid = (int)threadIdx.x;
    const int idx = (blockIdx.x * 256 + tid) * 4;          // 192 blocks * 1024
    const int proj = idx >> 16, rem = idx & 65535;
    const float* src = proj == 0 ? Wq : (proj == 1 ? Wk : Wv);
    float4 v = *(const float4*)(src + rem);
    *(ushort4*)(Wall + idx) = pack4(v.x, v.y, v.z, v.w);

    const int gid = blockIdx.x * 256 + tid;
    if (gid < 768) {
        float bb = gid < 256 ? bq[gid] : (gid < 512 ? bk[gid - 256] : bv[gid - 512]);
        bias_all[gid] = bb;
    }
}

// ---------------------------------------------------------------------------
// K0b: xT[b][tf][c] (bf16) = x[b][c][tf] (fp32).  64x64 tiles.
// ---------------------------------------------------------------------------
__global__ __launch_bounds__(256) void xt_kernel(
    const float* __restrict__ x, unsigned short* __restrict__ xT)
{
    const int tf0 = blockIdx.x * 64;
    const int c0  = blockIdx.y * 64;
    const int b   = blockIdx.z;
    const int tid = (int)threadIdx.x;
    __shared__ unsigned short ts[64][68];

    const float* xb = x + (size_t)(b * 256 + c0) * 65536 + tf0;
#pragma unroll
    for (int it = 0; it < 4; ++it) {
        int idx = it * 256 + tid;
        int cl = idx >> 4, tf4 = (idx & 15) * 4;
        float4 v = *(const float4*)(xb + (size_t)cl * 65536 + tf4);
        *(ushort4*)&ts[cl][tf4] = pack4(v.x, v.y, v.z, v.w);
    }
    __syncthreads();
    const int tfl = tid >> 2, c16 = (tid & 3) * 16;
    unsigned short* op = xT + ((size_t)b * 65536 + tf0 + tfl) * 256 + c0 + c16;
#pragma unroll
    for (int q = 0; q < 4; ++q) {
        int cl = c16 + q * 4;
        ushort4 v = make_ushort4(ts[cl][tfl], ts[cl+1][tfl], ts[cl+2][tfl], ts[cl+3][tfl]);
        *(ushort4*)(op + q * 4) = v;
    }
}

// ---------------------------------------------------------------------------
// K1: QKV projection as MFMA NT GEMM.
//   D[tf][r] = sum_c xT[b][tf][c] * Wall[r][c],  r = (proj,n,h)
// 128(tf) x 128(r) tile, BK=64, 4 waves (2x2), 4x4 fragments.
// Grid 1-D, XCD-chunked swizzle; ntile range [ntile_off, ntile_off+nb_n).
// Output: Qall + (proj - proj_base)*33554432, layout [m][t][e=h*64+f].
// ---------------------------------------------------------------------------
__global__ __launch_bounds__(256) void qkv_mfma(
    const unsigned short* __restrict__ xT, const unsigned short* __restrict__ Wall,
    const float* __restrict__ bias_all, unsigned short* __restrict__ outQ,
    int ntile_off, int nb_n, int proj_base)
{
    const int total = (int)gridDim.x;
    const int orig = (int)blockIdx.x;
    const int wgid = (orig & 7) * (total >> 3) + (orig >> 3);
    const int ntl = wgid % nb_n;
    const int rest = wgid / nb_n;            // 0..1023
    const int b = rest >> 9, tft = rest & 511;
    const int ntile = ntile_off + ntl;
    const int tfbase = tft * 128;
    const int nbase = ntile * 128;

    const int tid = (int)threadIdx.x;
    const int wid = tid >> 6, lane = tid & 63;
    const int wr = wid >> 1, wc = wid & 1;
    const int lo16 = lane & 15, hi4 = lane >> 4;

    __shared__ unsigned short As[128 * 64];
    __shared__ unsigned short Bs[128 * 64];

    f32x4 acc[4][4] = {};

    const unsigned short* arow = xT + ((size_t)b * 65536 + tfbase) * 256;
    const unsigned short* brow = Wall + (size_t)nbase * 256;

    const int srow = lane >> 3;
    const int scol = ((lane & 7) ^ srow) * 8;

    for (int cb = 0; cb < 256; cb += 64) {
#pragma unroll
        for (int i = 0; i < 4; ++i) {
            const int rb = wid * 32 + i * 8;
            gload_lds16(arow + (size_t)(rb + srow) * 256 + cb + scol, &As[rb * 64]);
            gload_lds16(brow + (size_t)(rb + srow) * 256 + cb + scol, &Bs[rb * 64]);
        }
        __syncthreads();
#pragma unroll
        for (int kk = 0; kk < 2; ++kk) {
            const int hc = (kk * 32 + hi4 * 8) ^ ((lane & 7) << 3);
            bf16x8 a[4], bb[4];
#pragma unroll
            for (int mi = 0; mi < 4; ++mi)
                a[mi] = *(const bf16x8*)&As[(wr * 64 + mi * 16 + lo16) * 64 + hc];
#pragma unroll
            for (int nj = 0; nj < 4; ++nj)
                bb[nj] = *(const bf16x8*)&Bs[(wc * 64 + nj * 16 + lo16) * 64 + hc];
#pragma unroll
            for (int mi = 0; mi < 4; ++mi)
#pragma unroll
                for (int nj = 0; nj < 4; ++nj)
                    mfma16(acc[mi][nj], a[mi], bb[nj]);
        }
        __syncthreads();
    }

    asm volatile("s_nop 7\n\ts_nop 7" ::: "memory");
    const int tf0 = tfbase + wr * 64;
#pragma unroll
    for (int nj = 0; nj < 4; ++nj) {
        const int r_col = nbase + wc * 64 + nj * 16 + lo16;
        const int projl = (r_col >> 8) - proj_base;
        const int rr = r_col & 255;
        const int mrow = (rr >> 6) * 2 + b;
        const int h = rr & 63;
        const float bv = bias_all[r_col];
        unsigned short* dst0 = outQ + (size_t)projl * 33554432
                             + (size_t)mrow * (T_ * E_) + h * 64;
#pragma unroll
        for (int mi = 0; mi < 4; ++mi) {
            const int tf = tf0 + mi * 16 + hi4 * 4;
            const int t = tf >> 6, f = tf & 63;
            *(ushort4*)(dst0 + (size_t)t * E_ + f) =
                pack4(acc[mi][nj][0] + bv, acc[mi][nj][1] + bv,
                      acc[mi][nj][2] + bv, acc[mi][nj][3] + bv);
        }
    }
}

// ---------------------------------------------------------------------------
// K2: scores, MFMA NT GEMM (unchanged from round 2)
// ---------------------------------------------------------------------------
__global__ __launch_bounds__(256) void scores_mfma(
    const unsigned short* __restrict__ Q, const unsigned short* __restrict__ K,
    unsigned short* __restrict__ S)
{
    const int m = blockIdx.z;
    const int tbase = blockIdx.y * 128;
    const int sbase = blockIdx.x * 128;
    const int tid = (int)threadIdx.x;
    const int wid = tid >> 6, lane = tid & 63;
    const int wr = wid >> 1, wc = wid & 1;
    const int lo16 = lane & 15, hi4 = lane >> 4;

    __shared__ unsigned short As[128 * 64];
    __shared__ unsigned short Bs[128 * 64];

    f32x4 acc[4][4] = {};

    const unsigned short* qrow = Q + ((size_t)m * T_ + tbase) * E_;
    const unsigned short* krow = K + ((size_t)m * T_ + sbase) * E_;

    const int srow = lane >> 3;
    const int scol = ((lane & 7) ^ srow) * 8;

    for (int eb = 0; eb < E_; eb += 64) {
#pragma unroll
        for (int i = 0; i < 4; ++i) {
            const int rb = wid * 32 + i * 8;
            gload_lds16(qrow + (size_t)(rb + srow) * E_ + eb + scol, &As[rb * 64]);
            gload_lds16(krow + (size_t)(rb + srow) * E_ + eb + scol, &Bs[rb * 64]);
        }
        __syncthreads();
#pragma unroll
        for (int kk = 0; kk < 2; ++kk) {
            const int hc = (kk * 32 + hi4 * 8) ^ ((lane & 7) << 3);
            bf16x8 a[4], bb[4];
#pragma unroll
            for (int mi = 0; mi < 4; ++mi)
                a[mi] = *(const bf16x8*)&As[(wr * 64 + mi * 16 + lo16) * 64 + hc];
#pragma unroll
            for (int nj = 0; nj < 4; ++nj)
                bb[nj] = *(const bf16x8*)&Bs[(wc * 64 + nj * 16 + lo16) * 64 + hc];
#pragma unroll
            for (int mi = 0; mi < 4; ++mi)
#pragma unroll
                for (int nj = 0; nj < 4; ++nj)
                    mfma16(acc[mi][nj], a[mi], bb[nj]);
        }
        __syncthreads();
    }

    asm volatile("s_nop 7\n\ts_nop 7" ::: "memory");
#pragma unroll
    for (int mi = 0; mi < 4; ++mi)
#pragma unroll
        for (int r = 0; r < 4; ++r) {
            int trow = tbase + wr * 64 + mi * 16 + hi4 * 4 + r;
            unsigned short* sp = S + ((size_t)m * T_ + trow) * T_ + sbase + wc * 64 + lo16;
#pragma unroll
            for (int nj = 0; nj < 4; ++nj)
                sp[nj * 16] = bf16_rne(acc[mi][nj][r] * SCALE_);
        }
}

// ---------------------------------------------------------------------------
// K3: row softmax (unchanged)
// ---------------------------------------------------------------------------
__global__ __launch_bounds__(256) void softmax_kernel(
    const unsigned short* __restrict__ S, unsigned short* __restrict__ A)
{
    const size_t rowoff = ((size_t)blockIdx.y * T_ + blockIdx.x) * T_;
    const int tid = (int)threadIdx.x;
    const int wid = tid >> 6, lane = tid & 63;

    __shared__ float redmx[4];
    __shared__ float redsm[4];

    float4 v = up4(*(const ushort4*)(S + rowoff + tid * 4));
    float mx = fmaxf(fmaxf(v.x, v.y), fmaxf(v.z, v.w));
#pragma unroll
    for (int off = 32; off > 0; off >>= 1) mx = fmaxf(mx, __shfl_xor(mx, off));
    if (lane == 0) redmx[wid] = mx;
    __syncthreads();
    mx = fmaxf(fmaxf(redmx[0], redmx[1]), fmaxf(redmx[2], redmx[3]));

    float e0 = __expf(v.x - mx), e1 = __expf(v.y - mx);
    float e2 = __expf(v.z - mx), e3 = __expf(v.w - mx);
    float sm = (e0 + e1) + (e2 + e3);
#pragma unroll
    for (int off = 32; off > 0; off >>= 1) sm += __shfl_xor(sm, off);
    if (lane == 0) redsm[wid] = sm;
    __syncthreads();
    sm = (redsm[0] + redsm[1]) + (redsm[2] + redsm[3]);
    float inv = 1.0f / sm;
    *(ushort4*)(A + rowoff + tid * 4) = pack4(e0 * inv, e1 * inv, e2 * inv, e3 * inv);
}

// ---------------------------------------------------------------------------
// K3b: V transpose (unchanged)
// ---------------------------------------------------------------------------
__global__ __launch_bounds__(256) void vt_kernel(
    const unsigned short* __restrict__ V, unsigned short* __restrict__ Vt)
{
    const int m = blockIdx.z;
    const int d0 = blockIdx.x * 64;
    const int s0 = blockIdx.y * 64;
    const int tid = (int)threadIdx.x;
    __shared__ unsigned short ts[64][68];

    const unsigned short* vp = V + (size_t)m * T_ * E_;
#pragma unroll
    for (int it = 0; it < 4; ++it) {
        int idx = it * 256 + tid;
        int sl = idx >> 4, d4 = (idx & 15) * 4;
        *(ushort4*)&ts[sl][d4] = *(const ushort4*)&vp[(size_t)(s0 + sl) * E_ + d0 + d4];
    }
    __syncthreads();
    unsigned short* op = Vt + (size_t)m * E_ * T_;
    const int dl = tid >> 2, s16 = (tid & 3) * 16;
#pragma unroll
    for (int q = 0; q < 4; ++q) {
        int s4 = s16 + q * 4;
        ushort4 v = make_ushort4(ts[s4][dl], ts[s4+1][dl], ts[s4+2][dl], ts[s4+3][dl]);
        *(ushort4*)&op[(size_t)(d0 + dl) * T_ + s0 + s4] = v;
    }
}

// ---------------------------------------------------------------------------
// K4: PV, MFMA NT GEMM vs Vt (unchanged)
// ---------------------------------------------------------------------------
__global__ __launch_bounds__(256) void pv_mfma(
    const unsigned short* __restrict__ A, const unsigned short* __restrict__ Vt,
    unsigned short* __restrict__ G)
{
    const int m = blockIdx.z;
    const int nh = m >> 1, b = m & 1;
    const int tbase = blockIdx.y * 128;
    const int dbase = blockIdx.x * 128;
    const int tid = (int)threadIdx.x;
    const int wid = tid >> 6, lane = tid & 63;
    const int wr = wid >> 1, wc = wid & 1;
    const int lo16 = lane & 15, hi4 = lane >> 4;

    __shared__ unsigned short As[128 * 64];
    __shared__ unsigned short Bs[128 * 64];

    f32x4 acc[4][4] = {};

    const unsigned short* arow = A  + ((size_t)m * T_ + tbase) * T_;
    const unsigned short* vrow = Vt + (size_t)m * E_ * T_ + (size_t)dbase * T_;

    const int srow = lane >> 3;
    const int scol = ((lane & 7) ^ srow) * 8;

    for (int sb = 0; sb < T_; sb += 64) {
#pragma unroll
        for (int i = 0; i < 4; ++i) {
            const int rb = wid * 32 + i * 8;
            gload_lds16(arow + (size_t)(rb + srow) * T_ + sb + scol, &As[rb * 64]);
            gload_lds16(vrow + (size_t)(rb + srow) * T_ + sb + scol, &Bs[rb * 64]);
        }
        __syncthreads();
#pragma unroll
        for (int kk = 0; kk < 2; ++kk) {
            const int hc = (kk * 32 + hi4 * 8) ^ ((lane & 7) << 3);
            bf16x8 a[4], bb[4];
#pragma unroll
            for (int mi = 0; mi < 4; ++mi)
                a[mi] = *(const bf16x8*)&As[(wr * 64 + mi * 16 + lo16) * 64 + hc];
#pragma unroll
            for (int nj = 0; nj < 4; ++nj)
                bb[nj] = *(const bf16x8*)&Bs[(wc * 64 + nj * 16 + lo16) * 64 + hc];
#pragma unroll
            for (int mi = 0; mi < 4; ++mi)
#pragma unroll
                for (int nj = 0; nj < 4; ++nj)
                    mfma16(acc[mi][nj], a[mi], bb[nj]);
        }
        __syncthreads();
    }

    asm volatile("s_nop 7\n\ts_nop 7" ::: "memory");
    const int cb   = nh * 64 + (dbase >> 6) + wc;
    const int t2lo = (tbase >> 6) + wr;
#pragma unroll
    for (int mi = 0; mi < 4; ++mi) {
        const int tl = mi * 16 + hi4 * 4;
#pragma unroll
        for (int nj = 0; nj < 4; ++nj) {
            const int d63 = nj * 16 + lo16;
            size_t addr = (((size_t)(b * 256 + cb)) * 1024 + d63 * 16 + t2lo) * 64 + tl;
            *(ushort4*)&G[addr] = pack4(acc[mi][nj][0], acc[mi][nj][1],
                                        acc[mi][nj][2], acc[mi][nj][3]);
        }
    }
}

// ---------------------------------------------------------------------------
// K5: out projection + bias + residual (unchanged)
// ---------------------------------------------------------------------------
__global__ __launch_bounds__(256) void outproj_kernel(
    const unsigned short* __restrict__ G, const float* __restrict__ Wp,
    const float* __restrict__ bp, const float* __restrict__ x,
    float* __restrict__ out)
{
    const int t = blockIdx.x;
    const int b = blockIdx.y;
    const int tid = (int)threadIdx.x;
    const int og = tid >> 3, fg = tid & 7;
    const int o0 = og * 8, f0 = fg * 8;

    __shared__ float gs[32][64];
    __shared__ float wps[32][256];

    float acc[8][8];
#pragma unroll
    for (int j = 0; j < 8; ++j)
#pragma unroll
        for (int i = 0; i < 8; ++i) acc[j][i] = 0.f;

    const unsigned short* gb = G + (size_t)b * (C_ * T_ * F_) + (size_t)t * F_;

    for (int ck = 0; ck < 8; ++ck) {
        const int cb = ck * 32;
#pragma unroll
        for (int it = 0; it < 2; ++it) {
            int idx = it * 256 + tid;
            int cc = idx >> 4, f4 = (idx & 15) * 4;
            *(float4*)&gs[cc][f4] = up4(*(const ushort4*)(gb + (size_t)(cb + cc) * (T_ * F_) + f4));
        }
#pragma unroll
        for (int cg = 0; cg < 8; ++cg) {
            float4 w4 = *(const float4*)(Wp + (size_t)tid * 256 + cb + cg * 4);
            wps[cg*4+0][tid] = w4.x; wps[cg*4+1][tid] = w4.y;
            wps[cg*4+2][tid] = w4.z; wps[cg*4+3][tid] = w4.w;
        }
        __syncthreads();
        for (int cc = 0; cc < 32; ++cc) {
            float4 g0 = *(float4*)&gs[cc][f0];
            float4 g1 = *(float4*)&gs[cc][f0 + 4];
            float gv[8] = {g0.x, g0.y, g0.z, g0.w, g1.x, g1.y, g1.z, g1.w};
            float4 w0 = *(float4*)&wps[cc][o0];
            float4 w1 = *(float4*)&wps[cc][o0 + 4];
            float wv[8] = {w0.x, w0.y, w0.z, w0.w, w1.x, w1.y, w1.z, w1.w};
#pragma unroll
            for (int j = 0; j < 8; ++j)
#pragma unroll
                for (int i = 0; i < 8; ++i)
                    acc[j][i] = fmaf(wv[j], gv[i], acc[j][i]);
        }
        __syncthreads();
    }

    const float* xrow = x   + (size_t)b * (C_ * T_ * F_) + (size_t)t * F_;
    float* orow       = out + (size_t)b * (C_ * T_ * F_) + (size_t)t * F_;
#pragma unroll
    for (int j = 0; j < 8; ++j) {
        int o = o0 + j;
        float bias = bp[o];
        const float* xp = xrow + (size_t)o * (T_ * F_) + f0;
        float* op       = orow + (size_t)o * (T_ * F_) + f0;
        float4 xv0 = *(const float4*)xp;
        float4 xv1 = *(const float4*)(xp + 4);
        float4 r0 = make_float4(acc[j][0]+bias+xv0.x, acc[j][1]+bias+xv0.y,
                                acc[j][2]+bias+xv0.z, acc[j][3]+bias+xv0.w);
        float4 r1 = make_float4(acc[j][4]+bias+xv1.x, acc[j][5]+bias+xv1.y,
                                acc[j][6]+bias+xv1.z, acc[j][7]+bias+xv1.w);
        *(float4*)op       = r0;
        *(float4*)(op + 4) = r1;
    }
}

// ---------------------------------------------------------------------------
extern "C" void kernel_launch(void* const* d_in, const int* in_sizes, int n_in,
                              void* d_out, int out_size, void* d_ws, size_t ws_size,
                              hipStream_t stream) {
    const float* x  = (const float*)d_in[0];
    const float* Wq = (const float*)d_in[1];
    const float* bq = (const float*)d_in[2];
    const float* Wk = (const float*)d_in[3];
    const float* bk = (const float*)d_in[4];
    const float* Wv = (const float*)d_in[5];
    const float* bv = (const float*)d_in[6];
    const float* Wp = (const float*)d_in[7];
    const float* bp = (const float*)d_in[8];
    float* out = (float*)d_out;

    // workspace layout (peak 224.4 MB; proven budget >= 235 MB from round 0)
    char* ws = (char*)d_ws;
    unsigned short* Q    = (unsigned short*)(ws);                 // R0: Q, later V
    unsigned short* K    = (unsigned short*)(ws + 67108864);      // R1: K, later Vt
    unsigned short* xT   = (unsigned short*)(ws + 134217728);     // R2: xT, later G
    unsigned short* S    = (unsigned short*)(ws + 201326592);     // 16 MB
    unsigned short* A    = (unsigned short*)(ws + 218103808);     // 16 MB
    unsigned short* Wall = (unsigned short*)(ws + 234881024);     // 393 KB
    float* bias_all      = (float*)(ws + 235274240);              // 3 KB
    unsigned short* V  = Q;    // written after scores (Q dead)
    unsigned short* Vt = K;    // written after scores (K dead)
    unsigned short* G  = xT;   // written after qkv_V (xT dead)

    wconv_kernel<<<192, 256, 0, stream>>>(Wq, Wk, Wv, bq, bk, bv, Wall, bias_all);
    xt_kernel<<<dim3(1024, 4, 2), 256, 0, stream>>>(x, xT);
    // Q,K (ntiles 0..3 -> proj 0,1; contiguous regions R0,R1)
    qkv_mfma<<<4096, 256, 0, stream>>>(xT, Wall, bias_all, Q, 0, 4, 0);
    scores_mfma<<<dim3(8, 8, M_), 256, 0, stream>>>(Q, K, S);
    // V (ntiles 4,5 -> proj 2), into R0 (Q dead after scores)
    qkv_mfma<<<2048, 256, 0, stream>>>(xT, Wall, bias_all, V, 4, 2, 2);
    softmax_kernel<<<dim3(T_, M_), 256, 0, stream>>>(S, A);
    vt_kernel<<<dim3(64, 16, M_), 256, 0, stream>>>(V, Vt);
    pv_mfma<<<dim3(32, 8, M_), 256, 0, stream>>>(A, Vt, G);
    outproj_kernel<<<dim3(T_, B_), 256, 0, stream>>>(G, Wp, bp, x, out);
}

// Round 4
// 429.272 us; speedup vs baseline: 5.7223x; 1.2436x over previous
//
#include <hip/hip_runtime.h>

#define DI __device__ __forceinline__

// Problem constants (B,C,T,F)=(2,256,1024,64), N=4, HID=64
static constexpr int B_ = 2;
static constexpr int C_ = 256;
static constexpr int T_ = 1024;
static constexpr int F_ = 64;
static constexpr int M_ = 8;      // N_*B_
static constexpr int E_ = 4096;   // HID*F = (C/N)*F
static constexpr float SCALE_ = 1.0f / 64.0f;   // 1/sqrt(4096)

typedef __attribute__((ext_vector_type(8))) short bf16x8;
typedef __attribute__((ext_vector_type(4))) float f32x4;

DI unsigned short bf16_rne(float f) {
    unsigned int u = __float_as_uint(f);
    return (unsigned short)((u + 0x7FFFu + ((u >> 16) & 1u)) >> 16);
}
DI float bf2f(unsigned short h) { return __uint_as_float(((unsigned int)h) << 16); }
DI ushort4 pack4(float a, float b, float c, float d) {
    return make_ushort4(bf16_rne(a), bf16_rne(b), bf16_rne(c), bf16_rne(d));
}
DI float4 up4(ushort4 u) {
    return make_float4(bf2f(u.x), bf2f(u.y), bf2f(u.z), bf2f(u.w));
}

// async global->LDS, 16B per lane; LDS dest = wave-uniform base + lane*16
DI void gload_lds16(const unsigned short* g, unsigned short* l) {
    __builtin_amdgcn_global_load_lds(
        (const __attribute__((address_space(1))) unsigned int*)g,
        (__attribute__((address_space(3))) unsigned int*)l, 16, 0, 0);
}

DI void mfma16(f32x4& acc, bf16x8 a, bf16x8 b) {
    asm("v_mfma_f32_16x16x32_bf16 %0, %1, %2, %0" : "+v"(acc) : "v"(a), "v"(b));
}

// ---------------------------------------------------------------------------
// K0: convert Wq|Wk|Wv -> Wall bf16 [768][256], Wp -> Wpb bf16 [256][256],
//     bias_all[768] = bq|bk|bv.
// blocks 0..191: Wall.  blocks 192..255: Wpb.
// ---------------------------------------------------------------------------
__global__ __launch_bounds__(256) void wconv_kernel(
    const float* __restrict__ Wq, const float* __restrict__ Wk,
    const float* __restrict__ Wv, const float* __restrict__ Wp,
    const float* __restrict__ bq, const float* __restrict__ bk,
    const float* __restrict__ bv,
    unsigned short* __restrict__ Wall, unsigned short* __restrict__ Wpb,
    float* __restrict__ bias_all)
{
    const int tid = (int)threadIdx.x;
    const int bid = (int)blockIdx.x;
    if (bid < 192) {
        const int idx = (bid * 256 + tid) * 4;
        const int proj = idx >> 16, rem = idx & 65535;
        const float* src = proj == 0 ? Wq : (proj == 1 ? Wk : Wv);
        float4 v = *(const float4*)(src + rem);
        *(ushort4*)(Wall + idx) = pack4(v.x, v.y, v.z, v.w);
        const int gid = bid * 256 + tid;
        if (gid < 768) {
            float bb = gid < 256 ? bq[gid] : (gid < 512 ? bk[gid - 256] : bv[gid - 512]);
            bias_all[gid] = bb;
        }
    } else {
        const int idx = ((bid - 192) * 256 + tid) * 4;     // 64 blocks * 1024 = 65536
        float4 v = *(const float4*)(Wp + idx);
        *(ushort4*)(Wpb + idx) = pack4(v.x, v.y, v.z, v.w);
    }
}

// ---------------------------------------------------------------------------
// K0b: xT[b][tf][c] (bf16) = x[b][c][tf] (fp32).  64x64 tiles.
// ---------------------------------------------------------------------------
__global__ __launch_bounds__(256) void xt_kernel(
    const float* __restrict__ x, unsigned short* __restrict__ xT)
{
    const int tf0 = blockIdx.x * 64;
    const int c0  = blockIdx.y * 64;
    const int b   = blockIdx.z;
    const int tid = (int)threadIdx.x;
    __shared__ unsigned short ts[64][68];

    const float* xb = x + (size_t)(b * 256 + c0) * 65536 + tf0;
#pragma unroll
    for (int it = 0; it < 4; ++it) {
        int idx = it * 256 + tid;
        int cl = idx >> 4, tf4 = (idx & 15) * 4;
        float4 v = *(const float4*)(xb + (size_t)cl * 65536 + tf4);
        *(ushort4*)&ts[cl][tf4] = pack4(v.x, v.y, v.z, v.w);
    }
    __syncthreads();
    const int tfl = tid >> 2, c16 = (tid & 3) * 16;
    unsigned short* op = xT + ((size_t)b * 65536 + tf0 + tfl) * 256 + c0 + c16;
#pragma unroll
    for (int q = 0; q < 4; ++q) {
        int cl = c16 + q * 4;
        ushort4 v = make_ushort4(ts[cl][tfl], ts[cl+1][tfl], ts[cl+2][tfl], ts[cl+3][tfl]);
        *(ushort4*)(op + q * 4) = v;
    }
}

// ---------------------------------------------------------------------------
// K1: QKV projection as MFMA NT GEMM (unchanged from round 3).
// ---------------------------------------------------------------------------
__global__ __launch_bounds__(256) void qkv_mfma(
    const unsigned short* __restrict__ xT, const unsigned short* __restrict__ Wall,
    const float* __restrict__ bias_all, unsigned short* __restrict__ outQ,
    int ntile_off, int nb_n, int proj_base)
{
    const int total = (int)gridDim.x;
    const int orig = (int)blockIdx.x;
    const int wgid = (orig & 7) * (total >> 3) + (orig >> 3);
    const int ntl = wgid % nb_n;
    const int rest = wgid / nb_n;
    const int b = rest >> 9, tft = rest & 511;
    const int ntile = ntile_off + ntl;
    const int tfbase = tft * 128;
    const int nbase = ntile * 128;

    const int tid = (int)threadIdx.x;
    const int wid = tid >> 6, lane = tid & 63;
    const int wr = wid >> 1, wc = wid & 1;
    const int lo16 = lane & 15, hi4 = lane >> 4;

    __shared__ unsigned short As[128 * 64];
    __shared__ unsigned short Bs[128 * 64];

    f32x4 acc[4][4] = {};

    const unsigned short* arow = xT + ((size_t)b * 65536 + tfbase) * 256;
    const unsigned short* brow = Wall + (size_t)nbase * 256;

    const int srow = lane >> 3;
    const int scol = ((lane & 7) ^ srow) * 8;

    for (int cb = 0; cb < 256; cb += 64) {
#pragma unroll
        for (int i = 0; i < 4; ++i) {
            const int rb = wid * 32 + i * 8;
            gload_lds16(arow + (size_t)(rb + srow) * 256 + cb + scol, &As[rb * 64]);
            gload_lds16(brow + (size_t)(rb + srow) * 256 + cb + scol, &Bs[rb * 64]);
        }
        __syncthreads();
#pragma unroll
        for (int kk = 0; kk < 2; ++kk) {
            const int hc = (kk * 32 + hi4 * 8) ^ ((lane & 7) << 3);
            bf16x8 a[4], bb[4];
#pragma unroll
            for (int mi = 0; mi < 4; ++mi)
                a[mi] = *(const bf16x8*)&As[(wr * 64 + mi * 16 + lo16) * 64 + hc];
#pragma unroll
            for (int nj = 0; nj < 4; ++nj)
                bb[nj] = *(const bf16x8*)&Bs[(wc * 64 + nj * 16 + lo16) * 64 + hc];
#pragma unroll
            for (int mi = 0; mi < 4; ++mi)
#pragma unroll
                for (int nj = 0; nj < 4; ++nj)
                    mfma16(acc[mi][nj], a[mi], bb[nj]);
        }
        __syncthreads();
    }

    asm volatile("s_nop 7\n\ts_nop 7" ::: "memory");
    const int tf0 = tfbase + wr * 64;
#pragma unroll
    for (int nj = 0; nj < 4; ++nj) {
        const int r_col = nbase + wc * 64 + nj * 16 + lo16;
        const int projl = (r_col >> 8) - proj_base;
        const int rr = r_col & 255;
        const int mrow = (rr >> 6) * 2 + b;
        const int h = rr & 63;
        const float bv = bias_all[r_col];
        unsigned short* dst0 = outQ + (size_t)projl * 33554432
                             + (size_t)mrow * (T_ * E_) + h * 64;
#pragma unroll
        for (int mi = 0; mi < 4; ++mi) {
            const int tf = tf0 + mi * 16 + hi4 * 4;
            const int t = tf >> 6, f = tf & 63;
            *(ushort4*)(dst0 + (size_t)t * E_ + f) =
                pack4(acc[mi][nj][0] + bv, acc[mi][nj][1] + bv,
                      acc[mi][nj][2] + bv, acc[mi][nj][3] + bv);
        }
    }
}

// ---------------------------------------------------------------------------
// K2: scores, MFMA NT GEMM (unchanged)
// ---------------------------------------------------------------------------
__global__ __launch_bounds__(256) void scores_mfma(
    const unsigned short* __restrict__ Q, const unsigned short* __restrict__ K,
    unsigned short* __restrict__ S)
{
    const int m = blockIdx.z;
    const int tbase = blockIdx.y * 128;
    const int sbase = blockIdx.x * 128;
    const int tid = (int)threadIdx.x;
    const int wid = tid >> 6, lane = tid & 63;
    const int wr = wid >> 1, wc = wid & 1;
    const int lo16 = lane & 15, hi4 = lane >> 4;

    __shared__ unsigned short As[128 * 64];
    __shared__ unsigned short Bs[128 * 64];

    f32x4 acc[4][4] = {};

    const unsigned short* qrow = Q + ((size_t)m * T_ + tbase) * E_;
    const unsigned short* krow = K + ((size_t)m * T_ + sbase) * E_;

    const int srow = lane >> 3;
    const int scol = ((lane & 7) ^ srow) * 8;

    for (int eb = 0; eb < E_; eb += 64) {
#pragma unroll
        for (int i = 0; i < 4; ++i) {
            const int rb = wid * 32 + i * 8;
            gload_lds16(qrow + (size_t)(rb + srow) * E_ + eb + scol, &As[rb * 64]);
            gload_lds16(krow + (size_t)(rb + srow) * E_ + eb + scol, &Bs[rb * 64]);
        }
        __syncthreads();
#pragma unroll
        for (int kk = 0; kk < 2; ++kk) {
            const int hc = (kk * 32 + hi4 * 8) ^ ((lane & 7) << 3);
            bf16x8 a[4], bb[4];
#pragma unroll
            for (int mi = 0; mi < 4; ++mi)
                a[mi] = *(const bf16x8*)&As[(wr * 64 + mi * 16 + lo16) * 64 + hc];
#pragma unroll
            for (int nj = 0; nj < 4; ++nj)
                bb[nj] = *(const bf16x8*)&Bs[(wc * 64 + nj * 16 + lo16) * 64 + hc];
#pragma unroll
            for (int mi = 0; mi < 4; ++mi)
#pragma unroll
                for (int nj = 0; nj < 4; ++nj)
                    mfma16(acc[mi][nj], a[mi], bb[nj]);
        }
        __syncthreads();
    }

    asm volatile("s_nop 7\n\ts_nop 7" ::: "memory");
#pragma unroll
    for (int mi = 0; mi < 4; ++mi)
#pragma unroll
        for (int r = 0; r < 4; ++r) {
            int trow = tbase + wr * 64 + mi * 16 + hi4 * 4 + r;
            unsigned short* sp = S + ((size_t)m * T_ + trow) * T_ + sbase + wc * 64 + lo16;
#pragma unroll
            for (int nj = 0; nj < 4; ++nj)
                sp[nj * 16] = bf16_rne(acc[mi][nj][r] * SCALE_);
        }
}

// ---------------------------------------------------------------------------
// K3: row softmax (unchanged)
// ---------------------------------------------------------------------------
__global__ __launch_bounds__(256) void softmax_kernel(
    const unsigned short* __restrict__ S, unsigned short* __restrict__ A)
{
    const size_t rowoff = ((size_t)blockIdx.y * T_ + blockIdx.x) * T_;
    const int tid = (int)threadIdx.x;
    const int wid = tid >> 6, lane = tid & 63;

    __shared__ float redmx[4];
    __shared__ float redsm[4];

    float4 v = up4(*(const ushort4*)(S + rowoff + tid * 4));
    float mx = fmaxf(fmaxf(v.x, v.y), fmaxf(v.z, v.w));
#pragma unroll
    for (int off = 32; off > 0; off >>= 1) mx = fmaxf(mx, __shfl_xor(mx, off));
    if (lane == 0) redmx[wid] = mx;
    __syncthreads();
    mx = fmaxf(fmaxf(redmx[0], redmx[1]), fmaxf(redmx[2], redmx[3]));

    float e0 = __expf(v.x - mx), e1 = __expf(v.y - mx);
    float e2 = __expf(v.z - mx), e3 = __expf(v.w - mx);
    float sm = (e0 + e1) + (e2 + e3);
#pragma unroll
    for (int off = 32; off > 0; off >>= 1) sm += __shfl_xor(sm, off);
    if (lane == 0) redsm[wid] = sm;
    __syncthreads();
    sm = (redsm[0] + redsm[1]) + (redsm[2] + redsm[3]);
    float inv = 1.0f / sm;
    *(ushort4*)(A + rowoff + tid * 4) = pack4(e0 * inv, e1 * inv, e2 * inv, e3 * inv);
}

// ---------------------------------------------------------------------------
// K3b: V transpose (unchanged)
// ---------------------------------------------------------------------------
__global__ __launch_bounds__(256) void vt_kernel(
    const unsigned short* __restrict__ V, unsigned short* __restrict__ Vt)
{
    const int m = blockIdx.z;
    const int d0 = blockIdx.x * 64;
    const int s0 = blockIdx.y * 64;
    const int tid = (int)threadIdx.x;
    __shared__ unsigned short ts[64][68];

    const unsigned short* vp = V + (size_t)m * T_ * E_;
#pragma unroll
    for (int it = 0; it < 4; ++it) {
        int idx = it * 256 + tid;
        int sl = idx >> 4, d4 = (idx & 15) * 4;
        *(ushort4*)&ts[sl][d4] = *(const ushort4*)&vp[(size_t)(s0 + sl) * E_ + d0 + d4];
    }
    __syncthreads();
    unsigned short* op = Vt + (size_t)m * E_ * T_;
    const int dl = tid >> 2, s16 = (tid & 3) * 16;
#pragma unroll
    for (int q = 0; q < 4; ++q) {
        int s4 = s16 + q * 4;
        ushort4 v = make_ushort4(ts[s4][dl], ts[s4+1][dl], ts[s4+2][dl], ts[s4+3][dl]);
        *(ushort4*)&op[(size_t)(d0 + dl) * T_ + s0 + s4] = v;
    }
}

// ---------------------------------------------------------------------------
// K4: PV, MFMA NT GEMM vs Vt (unchanged)
// ---------------------------------------------------------------------------
__global__ __launch_bounds__(256) void pv_mfma(
    const unsigned short* __restrict__ A, const unsigned short* __restrict__ Vt,
    unsigned short* __restrict__ G)
{
    const int m = blockIdx.z;
    const int nh = m >> 1, b = m & 1;
    const int tbase = blockIdx.y * 128;
    const int dbase = blockIdx.x * 128;
    const int tid = (int)threadIdx.x;
    const int wid = tid >> 6, lane = tid & 63;
    const int wr = wid >> 1, wc = wid & 1;
    const int lo16 = lane & 15, hi4 = lane >> 4;

    __shared__ unsigned short As[128 * 64];
    __shared__ unsigned short Bs[128 * 64];

    f32x4 acc[4][4] = {};

    const unsigned short* arow = A  + ((size_t)m * T_ + tbase) * T_;
    const unsigned short* vrow = Vt + (size_t)m * E_ * T_ + (size_t)dbase * T_;

    const int srow = lane >> 3;
    const int scol = ((lane & 7) ^ srow) * 8;

    for (int sb = 0; sb < T_; sb += 64) {
#pragma unroll
        for (int i = 0; i < 4; ++i) {
            const int rb = wid * 32 + i * 8;
            gload_lds16(arow + (size_t)(rb + srow) * T_ + sb + scol, &As[rb * 64]);
            gload_lds16(vrow + (size_t)(rb + srow) * T_ + sb + scol, &Bs[rb * 64]);
        }
        __syncthreads();
#pragma unroll
        for (int kk = 0; kk < 2; ++kk) {
            const int hc = (kk * 32 + hi4 * 8) ^ ((lane & 7) << 3);
            bf16x8 a[4], bb[4];
#pragma unroll
            for (int mi = 0; mi < 4; ++mi)
                a[mi] = *(const bf16x8*)&As[(wr * 64 + mi * 16 + lo16) * 64 + hc];
#pragma unroll
            for (int nj = 0; nj < 4; ++nj)
                bb[nj] = *(const bf16x8*)&Bs[(wc * 64 + nj * 16 + lo16) * 64 + hc];
#pragma unroll
            for (int mi = 0; mi < 4; ++mi)
#pragma unroll
                for (int nj = 0; nj < 4; ++nj)
                    mfma16(acc[mi][nj], a[mi], bb[nj]);
        }
        __syncthreads();
    }

    asm volatile("s_nop 7\n\ts_nop 7" ::: "memory");
    const int cb   = nh * 64 + (dbase >> 6) + wc;
    const int t2lo = (tbase >> 6) + wr;
#pragma unroll
    for (int mi = 0; mi < 4; ++mi) {
        const int tl = mi * 16 + hi4 * 4;
#pragma unroll
        for (int nj = 0; nj < 4; ++nj) {
            const int d63 = nj * 16 + lo16;
            size_t addr = (((size_t)(b * 256 + cb)) * 1024 + d63 * 16 + t2lo) * 64 + tl;
            *(ushort4*)&G[addr] = pack4(acc[mi][nj][0], acc[mi][nj][1],
                                        acc[mi][nj][2], acc[mi][nj][3]);
        }
    }
}

// ---------------------------------------------------------------------------
// K4b: G transpose.  GT[b][tf][c] = G[b][c][tf]   (bf16, 64x64 tiles)
// ---------------------------------------------------------------------------
__global__ __launch_bounds__(256) void gt_kernel(
    const unsigned short* __restrict__ G, unsigned short* __restrict__ GT)
{
    const int tf0 = blockIdx.x * 64;
    const int c0  = blockIdx.y * 64;
    const int b   = blockIdx.z;
    const int tid = (int)threadIdx.x;
    __shared__ unsigned short ts[64][68];

    const unsigned short* gb = G + (size_t)(b * 256 + c0) * 65536 + tf0;
#pragma unroll
    for (int it = 0; it < 4; ++it) {
        int idx = it * 256 + tid;
        int cl = idx >> 4, tf4 = (idx & 15) * 4;
        *(ushort4*)&ts[cl][tf4] = *(const ushort4*)(gb + (size_t)cl * 65536 + tf4);
    }
    __syncthreads();
    const int tfl = tid >> 2, c16 = (tid & 3) * 16;
    unsigned short* op = GT + ((size_t)b * 65536 + tf0 + tfl) * 256 + c0 + c16;
#pragma unroll
    for (int q = 0; q < 4; ++q) {
        int cl = c16 + q * 4;
        ushort4 v = make_ushort4(ts[cl][tfl], ts[cl+1][tfl], ts[cl+2][tfl], ts[cl+3][tfl]);
        *(ushort4*)(op + q * 4) = v;
    }
}

// ---------------------------------------------------------------------------
// K5: out projection, MFMA NT GEMM + fused bias + residual.
//   out[b][o][tf] = sum_c GT[b][tf][c]*Wpb[o][c] + bp[o] + x[b][o][tf]
// 128(tf) x 128(o) tile, BK=64, 4 waves, 4x4 fragments.
// ---------------------------------------------------------------------------
__global__ __launch_bounds__(256) void outproj_mfma(
    const unsigned short* __restrict__ GT, const unsigned short* __restrict__ Wpb,
    const float* __restrict__ bp, const float* __restrict__ x,
    float* __restrict__ out)
{
    const int tfbase = blockIdx.x * 128;
    const int obase  = blockIdx.y * 128;
    const int b      = blockIdx.z;
    const int tid = (int)threadIdx.x;
    const int wid = tid >> 6, lane = tid & 63;
    const int wr = wid >> 1, wc = wid & 1;
    const int lo16 = lane & 15, hi4 = lane >> 4;

    __shared__ unsigned short As[128 * 64];
    __shared__ unsigned short Bs[128 * 64];

    f32x4 acc[4][4] = {};

    const unsigned short* arow = GT + ((size_t)b * 65536 + tfbase) * 256;
    const unsigned short* brow = Wpb + (size_t)obase * 256;

    const int srow = lane >> 3;
    const int scol = ((lane & 7) ^ srow) * 8;

    for (int cb = 0; cb < 256; cb += 64) {
#pragma unroll
        for (int i = 0; i < 4; ++i) {
            const int rb = wid * 32 + i * 8;
            gload_lds16(arow + (size_t)(rb + srow) * 256 + cb + scol, &As[rb * 64]);
            gload_lds16(brow + (size_t)(rb + srow) * 256 + cb + scol, &Bs[rb * 64]);
        }
        __syncthreads();
#pragma unroll
        for (int kk = 0; kk < 2; ++kk) {
            const int hc = (kk * 32 + hi4 * 8) ^ ((lane & 7) << 3);
            bf16x8 a[4], bb[4];
#pragma unroll
            for (int mi = 0; mi < 4; ++mi)
                a[mi] = *(const bf16x8*)&As[(wr * 64 + mi * 16 + lo16) * 64 + hc];
#pragma unroll
            for (int nj = 0; nj < 4; ++nj)
                bb[nj] = *(const bf16x8*)&Bs[(wc * 64 + nj * 16 + lo16) * 64 + hc];
#pragma unroll
            for (int mi = 0; mi < 4; ++mi)
#pragma unroll
                for (int nj = 0; nj < 4; ++nj)
                    mfma16(acc[mi][nj], a[mi], bb[nj]);
        }
        __syncthreads();
    }

    asm volatile("s_nop 7\n\ts_nop 7" ::: "memory");
    // D: row = tf = tfbase + wr*64 + mi*16 + hi4*4 + r, col = o = obase + wc*64 + nj*16 + lo16
#pragma unroll
    for (int nj = 0; nj < 4; ++nj) {
        const int o = obase + wc * 64 + nj * 16 + lo16;
        const float bias = bp[o];
        const size_t rowb = ((size_t)(b * 256 + o)) * 65536;
#pragma unroll
        for (int mi = 0; mi < 4; ++mi) {
            const int tf = tfbase + wr * 64 + mi * 16 + hi4 * 4;
            float4 xv = *(const float4*)(x + rowb + tf);
            float4 r = make_float4(acc[mi][nj][0] + bias + xv.x,
                                   acc[mi][nj][1] + bias + xv.y,
                                   acc[mi][nj][2] + bias + xv.z,
                                   acc[mi][nj][3] + bias + xv.w);
            *(float4*)(out + rowb + tf) = r;
        }
    }
}

// ---------------------------------------------------------------------------
extern "C" void kernel_launch(void* const* d_in, const int* in_sizes, int n_in,
                              void* d_out, int out_size, void* d_ws, size_t ws_size,
                              hipStream_t stream) {
    const float* x  = (const float*)d_in[0];
    const float* Wq = (const float*)d_in[1];
    const float* bq = (const float*)d_in[2];
    const float* Wk = (const float*)d_in[3];
    const float* bk = (const float*)d_in[4];
    const float* Wv = (const float*)d_in[5];
    const float* bv = (const float*)d_in[6];
    const float* Wp = (const float*)d_in[7];
    const float* bp = (const float*)d_in[8];
    float* out = (float*)d_out;

    // workspace layout (peak ~235.4 MB)
    char* ws = (char*)d_ws;
    unsigned short* Q    = (unsigned short*)(ws);                 // R0: Q -> V -> GT
    unsigned short* K    = (unsigned short*)(ws + 67108864);      // R1: K -> Vt
    unsigned short* xT   = (unsigned short*)(ws + 134217728);     // R2: xT -> G
    unsigned short* S    = (unsigned short*)(ws + 201326592);     // 16 MB
    unsigned short* A    = (unsigned short*)(ws + 218103808);     // 16 MB
    unsigned short* Wall = (unsigned short*)(ws + 234881024);     // 393216 B
    float* bias_all      = (float*)(ws + 235274240);              // 3072 B
    unsigned short* Wpb  = (unsigned short*)(ws + 235277312);     // 131072 B
    unsigned short* V  = Q;    // written after scores (Q dead)
    unsigned short* Vt = K;    // written after scores (K dead)
    unsigned short* G  = xT;   // written after qkv_V (xT dead)
    unsigned short* GT = Q;    // written after pv (V dead after vt)

    wconv_kernel<<<256, 256, 0, stream>>>(Wq, Wk, Wv, Wp, bq, bk, bv, Wall, Wpb, bias_all);
    xt_kernel<<<dim3(1024, 4, 2), 256, 0, stream>>>(x, xT);
    qkv_mfma<<<4096, 256, 0, stream>>>(xT, Wall, bias_all, Q, 0, 4, 0);      // Q,K
    scores_mfma<<<dim3(8, 8, M_), 256, 0, stream>>>(Q, K, S);
    qkv_mfma<<<2048, 256, 0, stream>>>(xT, Wall, bias_all, V, 4, 2, 2);      // V
    softmax_kernel<<<dim3(T_, M_), 256, 0, stream>>>(S, A);
    vt_kernel<<<dim3(64, 16, M_), 256, 0, stream>>>(V, Vt);
    pv_mfma<<<dim3(32, 8, M_), 256, 0, stream>>>(A, Vt, G);
    gt_kernel<<<dim3(1024, 4, 2), 256, 0, stream>>>(G, GT);
    outproj_mfma<<<dim3(512, 2, 2), 256, 0, stream>>>(GT, Wpb, bp, x, out);
}